// Round 4
// baseline (11305.228 us; speedup 1.0000x reference)
//
#include <hip/hip_runtime.h>
#include <hip/hip_bf16.h>
#include <stdint.h>

#define N_NODES 50000
#define N_EDGES 1600000
#define D_FEAT  512
#define UNITS   512

static __device__ __forceinline__ float bfr(unsigned short u) {
    union { unsigned int i; float f; } c;
    c.i = ((unsigned int)u) << 16;
    return c.f;
}

static __device__ __forceinline__ unsigned short f2bfr(float f) {
    union { unsigned int i; float f; } c;
    c.f = f;
    unsigned int x = c.i;
    unsigned int rounded = x + 0x7FFF + ((x >> 16) & 1);
    return (unsigned short)(rounded >> 16);
}

// flags: [0]=X bf16, [1]=W bf16, [2]=bias bf16, [3]=ew bf16, [4]=esrc int64, [5]=edst int64
extern "C" __global__ void __launch_bounds__(64) GCN_detect(
    const void* X, const void* W, const void* bias, const void* ew,
    const void* esrc, const void* edst, int* flags)
{
    int t = threadIdx.x; // 0..63
    // sane bf16: zero, or exponent field in a plausible range for N(0,1)/U(0,1) data
    const unsigned short uX = ((const unsigned short*)X)[2 * t];
    const unsigned short uW = ((const unsigned short*)W)[2 * t];
    const unsigned short uB = ((const unsigned short*)bias)[2 * t];
    const unsigned short uE = ((const unsigned short*)ew)[2 * t];
    int eX = (uX >> 7) & 0xFF, eW = (uW >> 7) & 0xFF;
    int eB = (uB >> 7) & 0xFF, eE = (uE >> 7) & 0xFF;
    unsigned long long mX = __ballot((uX == 0) || (eX >= 100 && eX <= 140));
    unsigned long long mW = __ballot((uW == 0) || (eW >= 100 && eW <= 140));
    unsigned long long mB = __ballot((uB == 0) || (eB >= 100 && eB <= 140));
    unsigned long long mE = __ballot((uE == 0) || (eE >= 100 && eE <= 140));
    // int64 detection: odd int32 words are the high halves -> all zero for small int64s
    unsigned long long mS = __ballot(((const int*)esrc)[2 * t + 1] == 0);
    unsigned long long mD = __ballot(((const int*)edst)[2 * t + 1] == 0);
    if (t == 0) {
        flags[0] = (__popcll(mX) >= 56) ? 1 : 0;
        flags[1] = (__popcll(mW) >= 56) ? 1 : 0;
        flags[2] = (__popcll(mB) >= 56) ? 1 : 0;
        flags[3] = (__popcll(mE) >= 56) ? 1 : 0;
        flags[4] = (__popcll(mS) >= 56) ? 1 : 0;
        flags[5] = (__popcll(mD) >= 56) ? 1 : 0;
    }
}

// ---------------- init: agg = 0 (grid-stride)
extern "C" __global__ void __launch_bounds__(256) GCN_init(float* __restrict__ agg)
{
    const long long NE = (long long)N_NODES * UNITS;
    long long stride = (long long)gridDim.x * 256;
    for (long long i = (long long)blockIdx.x * 256 + threadIdx.x; i < NE; i += stride) {
        agg[i] = 0.0f;
    }
}

// ---------------- GEMM: h[M,N] = X[M,K] * W[K,N]; X/W bf16-or-fp32; h bf16; fp32 acc
#define BM 64
#define BN 64
#define BK 16

extern "C" __global__ void __launch_bounds__(256) GCN_gemm(
    const void* __restrict__ Ap, const void* __restrict__ Bp,
    unsigned short* __restrict__ Cu, int M, const int* __restrict__ flags)
{
    const int K = D_FEAT, N = UNITS;
    __shared__ float As[BM][BK];       // 64x16
    __shared__ float Bs[BK][BN + 1];   // 16x65 (pad)

    const int xbf = flags[0];
    const int wbf = flags[1];

    const unsigned short* Au = (const unsigned short*)Ap;
    const float*          Af = (const float*)Ap;
    const unsigned short* Bu = (const unsigned short*)Bp;
    const float*          Bf = (const float*)Bp;

    int tid = threadIdx.x;
    int tx = tid & 15, ty = tid >> 4;
    int by = blockIdx.x;   // row tile
    int bx = blockIdx.y;   // col tile
    int row0 = by * BM;

    float acc[4][4];
    for (int i = 0; i < 4; i++) {
        for (int j = 0; j < 4; j++) {
            acc[i][j] = 0.0f;
        }
    }

    for (int k0 = 0; k0 < K; k0 += BK) {
        if (xbf) {
            #pragma unroll
            for (int i = 0; i < 4; i++) {
                int e = tid * 4 + i;
                int r = e >> 4, c = e & 15;
                int gr = row0 + r;
                As[r][c] = (gr < M) ? bfr(Au[(long long)gr * K + k0 + c]) : 0.0f;
            }
        } else {
            #pragma unroll
            for (int i = 0; i < 4; i++) {
                int e = tid * 4 + i;
                int r = e >> 4, c = e & 15;
                int gr = row0 + r;
                As[r][c] = (gr < M) ? Af[(long long)gr * K + k0 + c] : 0.0f;
            }
        }
        if (wbf) {
            #pragma unroll
            for (int i = 0; i < 4; i++) {
                int e = tid * 4 + i;
                int r = e >> 6, c = e & 63;
                Bs[r][c] = bfr(Bu[(long long)(k0 + r) * N + bx * BN + c]);
            }
        } else {
            #pragma unroll
            for (int i = 0; i < 4; i++) {
                int e = tid * 4 + i;
                int r = e >> 6, c = e & 63;
                Bs[r][c] = Bf[(long long)(k0 + r) * N + bx * BN + c];
            }
        }
        __syncthreads();
        #pragma unroll
        for (int kk = 0; kk < BK; kk++) {
            float a[4], b[4];
            #pragma unroll
            for (int i = 0; i < 4; i++) {
                a[i] = As[ty * 4 + i][kk];
            }
            #pragma unroll
            for (int j = 0; j < 4; j++) {
                b[j] = Bs[kk][tx * 4 + j];
            }
            #pragma unroll
            for (int i = 0; i < 4; i++) {
                #pragma unroll
                for (int j = 0; j < 4; j++) {
                    acc[i][j] += a[i] * b[j];
                }
            }
        }
        __syncthreads();
    }

    #pragma unroll
    for (int i = 0; i < 4; i++) {
        int gr = row0 + ty * 4 + i;
        if (gr < M) {
            #pragma unroll
            for (int j = 0; j < 4; j++) {
                Cu[(long long)gr * N + bx * BN + tx * 4 + j] = f2bfr(acc[i][j]);
            }
        }
    }
}

// ---------------- Scatter-aggregate: agg[dst] += w * h[src]; fp32 atomics
extern "C" __global__ void __launch_bounds__(256) GCNConv_86311662780630_kernel(
    const unsigned short* __restrict__ h,
    const void* __restrict__ esrcp,
    const void* __restrict__ edstp,
    const void* __restrict__ ewp,
    float* __restrict__ agg,
    const int* __restrict__ flags)
{
    const int ewbf = flags[3];
    const int s64  = flags[4];
    const int d64  = flags[5];

    const long long total = (long long)N_EDGES * 128;
    long long stride = (long long)gridDim.x * 256;
    for (long long t = (long long)blockIdx.x * 256 + threadIdx.x; t < total; t += stride) {
        int e = (int)(t >> 7);
        int fo = ((int)t & 127) * 4;

        int src, dst;
        if (s64) {
            src = (int)((const long long*)esrcp)[e];
        } else {
            src = ((const int*)esrcp)[e];
        }
        if (d64) {
            dst = (int)((const long long*)edstp)[e];
        } else {
            dst = ((const int*)edstp)[e];
        }
        float w;
        if (ewbf) {
            w = bfr(((const unsigned short*)ewp)[e]);
        } else {
            w = ((const float*)ewp)[e];
        }

        const unsigned short* hp = h + (long long)src * UNITS + fo;
        ushort4 hv = *(const ushort4*)hp;

        float* ap = agg + (long long)dst * UNITS + fo;
        atomicAdd(ap + 0, w * bfr(hv.x));
        atomicAdd(ap + 1, w * bfr(hv.y));
        atomicAdd(ap + 2, w * bfr(hv.z));
        atomicAdd(ap + 3, w * bfr(hv.w));
    }
}

// ---------------- Epilogue: out(fp32) = relu(agg + bias)
extern "C" __global__ void __launch_bounds__(256) GCN_epi(
    const float* __restrict__ agg,
    const void* __restrict__ biasp,
    float* __restrict__ out,
    const int* __restrict__ flags)
{
    const int bbf = flags[2];
    const long long NQ = (long long)N_NODES * UNITS / 4;
    long long stride = (long long)gridDim.x * 256;
    for (long long q = (long long)blockIdx.x * 256 + threadIdx.x; q < NQ; q += stride) {
        long long i4 = q * 4;
        float4 a = *(const float4*)(agg + i4);
        int c = (int)(i4 & (UNITS - 1));
        float b0, b1, b2, b3;
        if (bbf) {
            const unsigned short* bu = (const unsigned short*)biasp;
            b0 = bfr(bu[c + 0]); b1 = bfr(bu[c + 1]);
            b2 = bfr(bu[c + 2]); b3 = bfr(bu[c + 3]);
        } else {
            const float* bf = (const float*)biasp;
            b0 = bf[c + 0]; b1 = bf[c + 1]; b2 = bf[c + 2]; b3 = bf[c + 3];
        }
        float v0 = a.x + b0, v1 = a.y + b1, v2 = a.z + b2, v3 = a.w + b3;
        v0 = v0 > 0.0f ? v0 : 0.0f;
        v1 = v1 > 0.0f ? v1 : 0.0f;
        v2 = v2 > 0.0f ? v2 : 0.0f;
        v3 = v3 > 0.0f ? v3 : 0.0f;
        float4 o; o.x = v0; o.y = v1; o.z = v2; o.w = v3;
        *(float4*)(out + i4) = o;
    }
}

extern "C" __attribute__((visibility("default")))
void kernel_launch(void* const* d_in, const int* in_sizes, int n_in,
                   void* d_out, int out_size, void* d_ws, size_t ws_size,
                   hipStream_t stream)
{
    const void* X    = d_in[0];
    const void* W    = d_in[1];
    const void* bias = d_in[2];
    const void* ew   = d_in[3];
    const void* esrc = d_in[4];
    const void* edst = d_in[5];
    float* out = (float*)d_out;   // fp32 output (ref=np computes in fp32)

    char* ws = (char*)d_ws;
    unsigned short* h = (unsigned short*)ws;                       // 51.2 MB bf16
    float* agg = (float*)(ws + (size_t)N_NODES * UNITS * 2);       // 102.4 MB fp32
    int* flags = (int*)(ws + (size_t)N_NODES * UNITS * 2
                           + (size_t)N_NODES * UNITS * 4);         // 24 B

    // 0) detect input dtypes (1 wave)
    GCN_detect<<<1, 64, 0, stream>>>(X, W, bias, ew, esrc, edst, flags);

    // 1) agg = 0
    GCN_init<<<16384, 256, 0, stream>>>(agg);

    // 2) h = X @ W  (bf16 h, fp32 acc)
    {
        dim3 grid((N_NODES + BM - 1) / BM, UNITS / BN);
        GCN_gemm<<<grid, 256, 0, stream>>>(X, W, h, N_NODES, flags);
    }

    // 3) scatter-aggregate over edges
    GCNConv_86311662780630_kernel<<<16384, 256, 0, stream>>>(h, esrc, edst, ew, agg, flags);

    // 4) epilogue: out = relu(agg + bias), fp32
    GCN_epi<<<16384, 256, 0, stream>>>(agg, bias, out, flags);
}

// Round 5
// 1303.891 us; speedup vs baseline: 8.6704x; 8.6704x over previous
//
#include <hip/hip_runtime.h>
#include <hip/hip_bf16.h>
#include <stdint.h>

#define N_NODES 50000
#define N_EDGES 1600000
#define D_FEAT  512
#define UNITS   512

typedef __attribute__((ext_vector_type(8))) unsigned short u16x8;

static __device__ __forceinline__ float bfr(unsigned short u) {
    union { unsigned int i; float f; } c;
    c.i = ((unsigned int)u) << 16;
    return c.f;
}

static __device__ __forceinline__ unsigned short f2bfr(float f) {
    union { unsigned int i; float f; } c;
    c.f = f;
    unsigned int x = c.i;
    unsigned int rounded = x + 0x7FFF + ((x >> 16) & 1);
    return (unsigned short)(rounded >> 16);
}

// flags: [0]=X bf16, [1]=W bf16, [2]=bias bf16, [3]=ew bf16, [4]=esrc int64, [5]=edst int64
extern "C" __global__ void __launch_bounds__(64) GCN_detect(
    const void* X, const void* W, const void* bias, const void* ew,
    const void* esrc, const void* edst, int* flags)
{
    int t = threadIdx.x; // 0..63
    const unsigned short uX = ((const unsigned short*)X)[2 * t];
    const unsigned short uW = ((const unsigned short*)W)[2 * t];
    const unsigned short uB = ((const unsigned short*)bias)[2 * t];
    const unsigned short uE = ((const unsigned short*)ew)[2 * t];
    int eX = (uX >> 7) & 0xFF, eW = (uW >> 7) & 0xFF;
    int eB = (uB >> 7) & 0xFF, eE = (uE >> 7) & 0xFF;
    unsigned long long mX = __ballot((uX == 0) || (eX >= 100 && eX <= 140));
    unsigned long long mW = __ballot((uW == 0) || (eW >= 100 && eW <= 140));
    unsigned long long mB = __ballot((uB == 0) || (eB >= 100 && eB <= 140));
    unsigned long long mE = __ballot((uE == 0) || (eE >= 100 && eE <= 140));
    unsigned long long mS = __ballot(((const int*)esrc)[2 * t + 1] == 0);
    unsigned long long mD = __ballot(((const int*)edst)[2 * t + 1] == 0);
    if (t == 0) {
        flags[0] = (__popcll(mX) >= 56) ? 1 : 0;
        flags[1] = (__popcll(mW) >= 56) ? 1 : 0;
        flags[2] = (__popcll(mB) >= 56) ? 1 : 0;
        flags[3] = (__popcll(mE) >= 56) ? 1 : 0;
        flags[4] = (__popcll(mS) >= 56) ? 1 : 0;
        flags[5] = (__popcll(mD) >= 56) ? 1 : 0;
    }
}

// ---------------- zero the per-dst edge counts
extern "C" __global__ void __launch_bounds__(256) GCN_zero(int* __restrict__ counts)
{
    int i = blockIdx.x * 256 + threadIdx.x;
    if (i < N_NODES) counts[i] = 0;
}

// ---------------- histogram of dst
extern "C" __global__ void __launch_bounds__(256) GCN_hist(
    const void* __restrict__ edstp, int* __restrict__ counts,
    const int* __restrict__ flags)
{
    const int d64 = flags[5];
    int e = blockIdx.x * 256 + threadIdx.x;
    if (e >= N_EDGES) return;
    int dst;
    if (d64) {
        dst = (int)((const long long*)edstp)[e];
    } else {
        dst = ((const int*)edstp)[e];
    }
    atomicAdd(&counts[dst], 1);
}

// ---------------- exclusive prefix sum over counts -> row_ptr, row_fill (1 block)
extern "C" __global__ void __launch_bounds__(256) GCN_scan(
    const int* __restrict__ counts, int* __restrict__ row_ptr,
    int* __restrict__ row_fill)
{
    __shared__ int tmp[256];
    __shared__ int carry_s;
    int tid = threadIdx.x;
    if (tid == 0) carry_s = 0;
    __syncthreads();
    for (int base = 0; base < N_NODES; base += 256) {
        int idx = base + tid;
        int v = (idx < N_NODES) ? counts[idx] : 0;
        tmp[tid] = v;
        __syncthreads();
        for (int off = 1; off < 256; off <<= 1) {
            int t = (tid >= off) ? tmp[tid - off] : 0;
            __syncthreads();
            tmp[tid] += t;
            __syncthreads();
        }
        int carry = carry_s;
        if (idx < N_NODES) {
            int excl = carry + tmp[tid] - v;
            row_ptr[idx] = excl;
            row_fill[idx] = excl;
        }
        __syncthreads();
        if (tid == 255) carry_s = carry + tmp[255];
        __syncthreads();
    }
    if (tid == 0) row_ptr[N_NODES] = carry_s;
}

// ---------------- build CSR: place (src, w) grouped by dst
extern "C" __global__ void __launch_bounds__(256) GCN_build(
    const void* __restrict__ esrcp, const void* __restrict__ edstp,
    const void* __restrict__ ewp, int* __restrict__ row_fill,
    int* __restrict__ csr_src, float* __restrict__ csr_w,
    const int* __restrict__ flags)
{
    const int ewbf = flags[3];
    const int s64 = flags[4];
    const int d64 = flags[5];
    int e = blockIdx.x * 256 + threadIdx.x;
    if (e >= N_EDGES) return;
    int src, dst;
    if (s64) {
        src = (int)((const long long*)esrcp)[e];
    } else {
        src = ((const int*)esrcp)[e];
    }
    if (d64) {
        dst = (int)((const long long*)edstp)[e];
    } else {
        dst = ((const int*)edstp)[e];
    }
    float w;
    if (ewbf) {
        w = bfr(((const unsigned short*)ewp)[e]);
    } else {
        w = ((const float*)ewp)[e];
    }
    int pos = atomicAdd(&row_fill[dst], 1);
    csr_src[pos] = src;
    csr_w[pos] = w;
}

// ---------------- GEMM: h[M,N] = X[M,K] * W[K,N]; bf16-or-fp32 in; h bf16; fp32 acc
#define BM 64
#define BN 64
#define BK 16

extern "C" __global__ void __launch_bounds__(256) GCN_gemm(
    const void* __restrict__ Ap, const void* __restrict__ Bp,
    unsigned short* __restrict__ Cu, int M, const int* __restrict__ flags)
{
    const int K = D_FEAT, N = UNITS;
    __shared__ float As[BM][BK];       // 64x16
    __shared__ float Bs[BK][BN + 1];   // 16x65 (pad)

    const int xbf = flags[0];
    const int wbf = flags[1];

    const unsigned short* Au = (const unsigned short*)Ap;
    const float*          Af = (const float*)Ap;
    const unsigned short* Bu = (const unsigned short*)Bp;
    const float*          Bf = (const float*)Bp;

    int tid = threadIdx.x;
    int tx = tid & 15, ty = tid >> 4;
    int by = blockIdx.x;
    int bx = blockIdx.y;
    int row0 = by * BM;

    float acc[4][4];
    for (int i = 0; i < 4; i++) {
        for (int j = 0; j < 4; j++) {
            acc[i][j] = 0.0f;
        }
    }

    for (int k0 = 0; k0 < K; k0 += BK) {
        if (xbf) {
            #pragma unroll
            for (int i = 0; i < 4; i++) {
                int e = tid * 4 + i;
                int r = e >> 4, c = e & 15;
                int gr = row0 + r;
                As[r][c] = (gr < M) ? bfr(Au[(long long)gr * K + k0 + c]) : 0.0f;
            }
        } else {
            #pragma unroll
            for (int i = 0; i < 4; i++) {
                int e = tid * 4 + i;
                int r = e >> 4, c = e & 15;
                int gr = row0 + r;
                As[r][c] = (gr < M) ? Af[(long long)gr * K + k0 + c] : 0.0f;
            }
        }
        if (wbf) {
            #pragma unroll
            for (int i = 0; i < 4; i++) {
                int e = tid * 4 + i;
                int r = e >> 6, c = e & 63;
                Bs[r][c] = bfr(Bu[(long long)(k0 + r) * N + bx * BN + c]);
            }
        } else {
            #pragma unroll
            for (int i = 0; i < 4; i++) {
                int e = tid * 4 + i;
                int r = e >> 6, c = e & 63;
                Bs[r][c] = Bf[(long long)(k0 + r) * N + bx * BN + c];
            }
        }
        __syncthreads();
        #pragma unroll
        for (int kk = 0; kk < BK; kk++) {
            float a[4], b[4];
            #pragma unroll
            for (int i = 0; i < 4; i++) {
                a[i] = As[ty * 4 + i][kk];
            }
            #pragma unroll
            for (int j = 0; j < 4; j++) {
                b[j] = Bs[kk][tx * 4 + j];
            }
            #pragma unroll
            for (int i = 0; i < 4; i++) {
                #pragma unroll
                for (int j = 0; j < 4; j++) {
                    acc[i][j] += a[i] * b[j];
                }
            }
        }
        __syncthreads();
    }

    #pragma unroll
    for (int i = 0; i < 4; i++) {
        int gr = row0 + ty * 4 + i;
        if (gr < M) {
            #pragma unroll
            for (int j = 0; j < 4; j++) {
                Cu[(long long)gr * N + bx * BN + tx * 4 + j] = f2bfr(acc[i][j]);
            }
        }
    }
}

// ---------------- Aggregate: one wave per dst row, no atomics, fused bias+relu.
// lane owns 8 consecutive feats (16B bf16 load per edge), acc in regs.
extern "C" __global__ void __launch_bounds__(256) GCNConv_86311662780630_kernel(
    const unsigned short* __restrict__ h,
    const int* __restrict__ row_ptr,
    const int* __restrict__ csr_src,
    const float* __restrict__ csr_w,
    const void* __restrict__ biasp,
    float* __restrict__ out,
    const int* __restrict__ flags)
{
    const int bbf = flags[2];
    int wave = threadIdx.x >> 6;
    int lane = threadIdx.x & 63;
    int row = blockIdx.x * 4 + wave;
    if (row >= N_NODES) return;

    int beg = row_ptr[row];
    int end = row_ptr[row + 1];
    const int fo = lane * 8;

    float acc[8];
    #pragma unroll
    for (int j = 0; j < 8; j++) {
        acc[j] = 0.0f;
    }

    int e = beg;
    for (; e + 1 < end; e += 2) {
        int s0 = csr_src[e];
        int s1 = csr_src[e + 1];
        float w0 = csr_w[e];
        float w1 = csr_w[e + 1];
        u16x8 h0 = *(const u16x8*)(h + (long long)s0 * UNITS + fo);
        u16x8 h1 = *(const u16x8*)(h + (long long)s1 * UNITS + fo);
        #pragma unroll
        for (int j = 0; j < 8; j++) {
            acc[j] += w0 * bfr(h0[j]);
        }
        #pragma unroll
        for (int j = 0; j < 8; j++) {
            acc[j] += w1 * bfr(h1[j]);
        }
    }
    if (e < end) {
        int s0 = csr_src[e];
        float w0 = csr_w[e];
        u16x8 h0 = *(const u16x8*)(h + (long long)s0 * UNITS + fo);
        #pragma unroll
        for (int j = 0; j < 8; j++) {
            acc[j] += w0 * bfr(h0[j]);
        }
    }

    // fused bias + relu -> fp32 out
    float b[8];
    if (bbf) {
        const unsigned short* bu = (const unsigned short*)biasp;
        #pragma unroll
        for (int j = 0; j < 8; j++) {
            b[j] = bfr(bu[fo + j]);
        }
    } else {
        const float* bf = (const float*)biasp;
        #pragma unroll
        for (int j = 0; j < 8; j++) {
            b[j] = bf[fo + j];
        }
    }
    float4 o0, o1;
    float v;
    v = acc[0] + b[0]; o0.x = v > 0.0f ? v : 0.0f;
    v = acc[1] + b[1]; o0.y = v > 0.0f ? v : 0.0f;
    v = acc[2] + b[2]; o0.z = v > 0.0f ? v : 0.0f;
    v = acc[3] + b[3]; o0.w = v > 0.0f ? v : 0.0f;
    v = acc[4] + b[4]; o1.x = v > 0.0f ? v : 0.0f;
    v = acc[5] + b[5]; o1.y = v > 0.0f ? v : 0.0f;
    v = acc[6] + b[6]; o1.z = v > 0.0f ? v : 0.0f;
    v = acc[7] + b[7]; o1.w = v > 0.0f ? v : 0.0f;
    float* op = out + (long long)row * UNITS + fo;
    *(float4*)(op + 0) = o0;
    *(float4*)(op + 4) = o1;
}

extern "C" __attribute__((visibility("default")))
void kernel_launch(void* const* d_in, const int* in_sizes, int n_in,
                   void* d_out, int out_size, void* d_ws, size_t ws_size,
                   hipStream_t stream)
{
    const void* X    = d_in[0];
    const void* W    = d_in[1];
    const void* bias = d_in[2];
    const void* ew   = d_in[3];
    const void* esrc = d_in[4];
    const void* edst = d_in[5];
    float* out = (float*)d_out;

    // workspace layout (all 16B-aligned)
    char* ws = (char*)d_ws;
    size_t off = 0;
    unsigned short* h = (unsigned short*)(ws + off); off += (size_t)N_NODES * UNITS * 2;   // 51.2 MB
    int*   csr_src = (int*)(ws + off);   off += (size_t)N_EDGES * 4;                        // 6.4 MB
    float* csr_w   = (float*)(ws + off); off += (size_t)N_EDGES * 4;                        // 6.4 MB
    int*   counts  = (int*)(ws + off);   off += (size_t)N_NODES * 4;                        // 200 KB
    int*   row_ptr = (int*)(ws + off);   off += (size_t)(N_NODES + 1) * 4 + 12;             // 200 KB
    int*   row_fill= (int*)(ws + off);   off += (size_t)N_NODES * 4;                        // 200 KB
    int*   flags   = (int*)(ws + off);

    // 0) detect input dtypes (1 wave)
    GCN_detect<<<1, 64, 0, stream>>>(X, W, bias, ew, esrc, edst, flags);

    // 1) zero per-dst counts
    GCN_zero<<<(N_NODES + 255) / 256, 256, 0, stream>>>(counts);

    // 2) h = X @ W
    {
        dim3 grid((N_NODES + BM - 1) / BM, UNITS / BN);
        GCN_gemm<<<grid, 256, 0, stream>>>(X, W, h, N_NODES, flags);
    }

    // 3) histogram of dst
    GCN_hist<<<(N_EDGES + 255) / 256, 256, 0, stream>>>(edst, counts, flags);

    // 4) prefix sum -> row_ptr, row_fill
    GCN_scan<<<1, 256, 0, stream>>>(counts, row_ptr, row_fill);

    // 5) build CSR (src, w grouped by dst)
    GCN_build<<<(N_EDGES + 255) / 256, 256, 0, stream>>>(esrc, edst, ew, row_fill,
                                                         csr_src, csr_w, flags);

    // 6) aggregate + bias + relu -> out (wave per row, no atomics)
    GCNConv_86311662780630_kernel<<<(N_NODES + 3) / 4, 256, 0, stream>>>(
        h, row_ptr, csr_src, csr_w, bias, out, flags);
}

// Round 6
// 854.992 us; speedup vs baseline: 13.2226x; 1.5250x over previous
//
#include <hip/hip_runtime.h>
#include <hip/hip_bf16.h>
#include <stdint.h>

#define N_NODES 50000
#define N_EDGES 1600000
#define D_FEAT  512
#define UNITS   512

typedef __attribute__((ext_vector_type(8))) unsigned short u16x8;
typedef __attribute__((ext_vector_type(8))) short s16x8;
typedef __attribute__((ext_vector_type(4))) float f32x4;

static __device__ __forceinline__ float bfr(unsigned short u) {
    union { unsigned int i; float f; } c;
    c.i = ((unsigned int)u) << 16;
    return c.f;
}

static __device__ __forceinline__ unsigned short f2bfr(float f) {
    union { unsigned int i; float f; } c;
    c.f = f;
    unsigned int x = c.i;
    unsigned int rounded = x + 0x7FFF + ((x >> 16) & 1);
    return (unsigned short)(rounded >> 16);
}

// async 16B global -> LDS (width=16 verified on gfx950)
static __device__ __forceinline__ void gload16(const unsigned short* g, unsigned short* l) {
    __builtin_amdgcn_global_load_lds(
        (const __attribute__((address_space(1))) void*)g,
        (__attribute__((address_space(3))) void*)l, 16, 0, 0);
}

// flags: [0]=X bf16, [1]=W bf16, [2]=bias bf16, [3]=ew bf16, [4]=esrc int64, [5]=edst int64
extern "C" __global__ void __launch_bounds__(64) GCN_detect(
    const void* X, const void* W, const void* bias, const void* ew,
    const void* esrc, const void* edst, int* flags)
{
    int t = threadIdx.x;
    const unsigned short uX = ((const unsigned short*)X)[2 * t];
    const unsigned short uW = ((const unsigned short*)W)[2 * t];
    const unsigned short uB = ((const unsigned short*)bias)[2 * t];
    const unsigned short uE = ((const unsigned short*)ew)[2 * t];
    int eX = (uX >> 7) & 0xFF, eW = (uW >> 7) & 0xFF;
    int eB = (uB >> 7) & 0xFF, eE = (uE >> 7) & 0xFF;
    unsigned long long mX = __ballot((uX == 0) || (eX >= 100 && eX <= 140));
    unsigned long long mW = __ballot((uW == 0) || (eW >= 100 && eW <= 140));
    unsigned long long mB = __ballot((uB == 0) || (eB >= 100 && eB <= 140));
    unsigned long long mE = __ballot((uE == 0) || (eE >= 100 && eE <= 140));
    unsigned long long mS = __ballot(((const int*)esrc)[2 * t + 1] == 0);
    unsigned long long mD = __ballot(((const int*)edst)[2 * t + 1] == 0);
    if (t == 0) {
        flags[0] = (__popcll(mX) >= 56) ? 1 : 0;
        flags[1] = (__popcll(mW) >= 56) ? 1 : 0;
        flags[2] = (__popcll(mB) >= 56) ? 1 : 0;
        flags[3] = (__popcll(mE) >= 56) ? 1 : 0;
        flags[4] = (__popcll(mS) >= 56) ? 1 : 0;
        flags[5] = (__popcll(mD) >= 56) ? 1 : 0;
    }
}

// ---------------- zero per-dst counts
extern "C" __global__ void __launch_bounds__(256) GCN_zero(int* __restrict__ counts)
{
    int i = blockIdx.x * 256 + threadIdx.x;
    if (i < N_NODES) counts[i] = 0;
}

// ---------------- convert X -> bf16 (only runs work when X is fp32)
extern "C" __global__ void __launch_bounds__(256) GCN_xconv(
    const void* __restrict__ Xp, unsigned short* __restrict__ Xb,
    const int* __restrict__ flags)
{
    if (flags[0]) return; // already bf16, GEMM reads X directly
    const float4* Xf = (const float4*)Xp;
    const long long NQ = (long long)N_NODES * D_FEAT / 4;
    long long stride = (long long)gridDim.x * 256;
    for (long long q = (long long)blockIdx.x * 256 + threadIdx.x; q < NQ; q += stride) {
        float4 v = Xf[q];
        ushort4 o;
        o.x = f2bfr(v.x); o.y = f2bfr(v.y); o.z = f2bfr(v.z); o.w = f2bfr(v.w);
        *(ushort4*)(Xb + q * 4) = o;
    }
}

// ---------------- Wt[n][k] = bf16(W[k][n])  (512x512, LDS tile transpose)
extern "C" __global__ void __launch_bounds__(256) GCN_wt(
    const void* __restrict__ Wp, unsigned short* __restrict__ Wt,
    const int* __restrict__ flags)
{
    __shared__ unsigned short tile[64][65];
    const int wbf = flags[1];
    int k0 = blockIdx.x * 64, n0 = blockIdx.y * 64;
    int t = threadIdx.x;
    for (int p = 0; p < 16; p++) {
        int idx = p * 256 + t;
        int r = idx >> 6, c = idx & 63;
        unsigned short v;
        if (wbf) {
            v = ((const unsigned short*)Wp)[(long long)(k0 + r) * UNITS + n0 + c];
        } else {
            v = f2bfr(((const float*)Wp)[(long long)(k0 + r) * UNITS + n0 + c]);
        }
        tile[r][c] = v;
    }
    __syncthreads();
    for (int p = 0; p < 16; p++) {
        int idx = p * 256 + t;
        int r = idx >> 6, c = idx & 63;
        Wt[(long long)(n0 + r) * D_FEAT + k0 + c] = tile[c][r];
    }
}

// ---------------- histogram of dst
extern "C" __global__ void __launch_bounds__(256) GCN_hist(
    const void* __restrict__ edstp, int* __restrict__ counts,
    const int* __restrict__ flags)
{
    const int d64 = flags[5];
    int e = blockIdx.x * 256 + threadIdx.x;
    if (e >= N_EDGES) return;
    int dst;
    if (d64) {
        dst = (int)((const long long*)edstp)[e];
    } else {
        dst = ((const int*)edstp)[e];
    }
    atomicAdd(&counts[dst], 1);
}

// ---------------- exclusive prefix sum -> row_ptr, row_fill (1 block)
extern "C" __global__ void __launch_bounds__(256) GCN_scan(
    const int* __restrict__ counts, int* __restrict__ row_ptr,
    int* __restrict__ row_fill)
{
    __shared__ int tmp[256];
    __shared__ int carry_s;
    int tid = threadIdx.x;
    if (tid == 0) carry_s = 0;
    __syncthreads();
    for (int base = 0; base < N_NODES; base += 256) {
        int idx = base + tid;
        int v = (idx < N_NODES) ? counts[idx] : 0;
        tmp[tid] = v;
        __syncthreads();
        for (int off = 1; off < 256; off <<= 1) {
            int t = (tid >= off) ? tmp[tid - off] : 0;
            __syncthreads();
            tmp[tid] += t;
            __syncthreads();
        }
        int carry = carry_s;
        if (idx < N_NODES) {
            int excl = carry + tmp[tid] - v;
            row_ptr[idx] = excl;
            row_fill[idx] = excl;
        }
        __syncthreads();
        if (tid == 255) carry_s = carry + tmp[255];
        __syncthreads();
    }
    if (tid == 0) row_ptr[N_NODES] = carry_s;
}

// ---------------- build CSR
extern "C" __global__ void __launch_bounds__(256) GCN_build(
    const void* __restrict__ esrcp, const void* __restrict__ edstp,
    const void* __restrict__ ewp, int* __restrict__ row_fill,
    int* __restrict__ csr_src, float* __restrict__ csr_w,
    const int* __restrict__ flags)
{
    const int ewbf = flags[3];
    const int s64 = flags[4];
    const int d64 = flags[5];
    int e = blockIdx.x * 256 + threadIdx.x;
    if (e >= N_EDGES) return;
    int src, dst;
    if (s64) {
        src = (int)((const long long*)esrcp)[e];
    } else {
        src = ((const int*)esrcp)[e];
    }
    if (d64) {
        dst = (int)((const long long*)edstp)[e];
    } else {
        dst = ((const int*)edstp)[e];
    }
    float w;
    if (ewbf) {
        w = bfr(((const unsigned short*)ewp)[e]);
    } else {
        w = ((const float*)ewp)[e];
    }
    int pos = atomicAdd(&row_fill[dst], 1);
    csr_src[pos] = src;
    csr_w[pos] = w;
}

// ---------------- MFMA GEMM: h[M,N] = X[M,K] @ W[K,N], m97 structure
// 128x128 tile, BK=32, 4 waves (2x2), each wave 4x4 of 16x16x32 bf16 MFMA.
extern "C" __global__ void __launch_bounds__(256) GCN_gemm_mfma(
    const void* __restrict__ Xp, const unsigned short* __restrict__ Xb,
    const unsigned short* __restrict__ Wt,
    unsigned short* __restrict__ Cu, const int* __restrict__ flags)
{
    __shared__ unsigned short As[128 * 32];  // 8 KB, row-major [m][k]
    __shared__ unsigned short Bs[128 * 32];  // 8 KB, row-major [n][k]

    const unsigned short* Xsrc = flags[0] ? (const unsigned short*)Xp : Xb;

    const int tid  = threadIdx.x;
    const int wave = tid >> 6, lane = tid & 63;
    const int quad = lane >> 4, l16 = lane & 15;
    const int wm = wave >> 1, wn = wave & 1;
    const int row0 = blockIdx.y * 128;   // M tile
    const int n0   = blockIdx.x * 128;   // N tile

    f32x4 acc[4][4];
    #pragma unroll
    for (int i = 0; i < 4; i++) {
        #pragma unroll
        for (int j = 0; j < 4; j++) {
            acc[i][j] = (f32x4){0.0f, 0.0f, 0.0f, 0.0f};
        }
    }

    for (int k0 = 0; k0 < D_FEAT; k0 += 32) {
        // stage A (128x32) and B (128x32): 512 x 16B each, 256 threads x 2
        #pragma unroll
        for (int it = 0; it < 2; it++) {
            int flat = it * 256 + tid;          // 0..511
            int r = flat >> 2, cb = flat & 3;   // row, 8-elem chunk
            int gr = row0 + r;
            if (gr > N_NODES - 1) gr = N_NODES - 1;   // clamp (dup loads ok)
            gload16(Xsrc + (long long)gr * D_FEAT + k0 + cb * 8, As + flat * 8);
            gload16(Wt + (long long)(n0 + r) * D_FEAT + k0 + cb * 8, Bs + flat * 8);
        }
        __syncthreads();

        s16x8 a[4], b[4];
        #pragma unroll
        for (int i = 0; i < 4; i++) {
            a[i] = *(const s16x8*)(As + ((wm * 64 + i * 16 + l16) * 32 + quad * 8));
        }
        #pragma unroll
        for (int j = 0; j < 4; j++) {
            b[j] = *(const s16x8*)(Bs + ((wn * 64 + j * 16 + l16) * 32 + quad * 8));
        }
        #pragma unroll
        for (int i = 0; i < 4; i++) {
            #pragma unroll
            for (int j = 0; j < 4; j++) {
                acc[i][j] = __builtin_amdgcn_mfma_f32_16x16x32_bf16(
                    a[i], b[j], acc[i][j], 0, 0, 0);
            }
        }
        __syncthreads();
    }

    // epilogue: C/D layout col=lane&15, row=quad*4+reg (m89-verified)
    #pragma unroll
    for (int i = 0; i < 4; i++) {
        #pragma unroll
        for (int r = 0; r < 4; r++) {
            int gr = row0 + wm * 64 + i * 16 + quad * 4 + r;
            if (gr < N_NODES) {
                #pragma unroll
                for (int j = 0; j < 4; j++) {
                    int gc = n0 + wn * 64 + j * 16 + l16;
                    Cu[(long long)gr * UNITS + gc] = f2bfr(acc[i][j][r]);
                }
            }
        }
    }
}

// ---------------- Aggregate: one wave per dst row, no atomics, fused bias+relu
extern "C" __global__ void __launch_bounds__(256) GCNConv_86311662780630_kernel(
    const unsigned short* __restrict__ h,
    const int* __restrict__ row_ptr,
    const int* __restrict__ csr_src,
    const float* __restrict__ csr_w,
    const void* __restrict__ biasp,
    float* __restrict__ out,
    const int* __restrict__ flags)
{
    const int bbf = flags[2];
    int wave = threadIdx.x >> 6;
    int lane = threadIdx.x & 63;
    int row = blockIdx.x * 4 + wave;
    if (row >= N_NODES) return;

    int beg = row_ptr[row];
    int end = row_ptr[row + 1];
    const int fo = lane * 8;

    float acc[8];
    #pragma unroll
    for (int j = 0; j < 8; j++) {
        acc[j] = 0.0f;
    }

    int e = beg;
    for (; e + 1 < end; e += 2) {
        int s0 = csr_src[e];
        int s1 = csr_src[e + 1];
        float w0 = csr_w[e];
        float w1 = csr_w[e + 1];
        u16x8 h0 = *(const u16x8*)(h + (long long)s0 * UNITS + fo);
        u16x8 h1 = *(const u16x8*)(h + (long long)s1 * UNITS + fo);
        #pragma unroll
        for (int j = 0; j < 8; j++) {
            acc[j] += w0 * bfr(h0[j]);
        }
        #pragma unroll
        for (int j = 0; j < 8; j++) {
            acc[j] += w1 * bfr(h1[j]);
        }
    }
    if (e < end) {
        int s0 = csr_src[e];
        float w0 = csr_w[e];
        u16x8 h0 = *(const u16x8*)(h + (long long)s0 * UNITS + fo);
        #pragma unroll
        for (int j = 0; j < 8; j++) {
            acc[j] += w0 * bfr(h0[j]);
        }
    }

    float b[8];
    if (bbf) {
        const unsigned short* bu = (const unsigned short*)biasp;
        #pragma unroll
        for (int j = 0; j < 8; j++) {
            b[j] = bfr(bu[fo + j]);
        }
    } else {
        const float* bf = (const float*)biasp;
        #pragma unroll
        for (int j = 0; j < 8; j++) {
            b[j] = bf[fo + j];
        }
    }
    float4 o0, o1;
    float v;
    v = acc[0] + b[0]; o0.x = v > 0.0f ? v : 0.0f;
    v = acc[1] + b[1]; o0.y = v > 0.0f ? v : 0.0f;
    v = acc[2] + b[2]; o0.z = v > 0.0f ? v : 0.0f;
    v = acc[3] + b[3]; o0.w = v > 0.0f ? v : 0.0f;
    v = acc[4] + b[4]; o1.x = v > 0.0f ? v : 0.0f;
    v = acc[5] + b[5]; o1.y = v > 0.0f ? v : 0.0f;
    v = acc[6] + b[6]; o1.z = v > 0.0f ? v : 0.0f;
    v = acc[7] + b[7]; o1.w = v > 0.0f ? v : 0.0f;
    float* op = out + (long long)row * UNITS + fo;
    *(float4*)(op + 0) = o0;
    *(float4*)(op + 4) = o1;
}

extern "C" __attribute__((visibility("default")))
void kernel_launch(void* const* d_in, const int* in_sizes, int n_in,
                   void* d_out, int out_size, void* d_ws, size_t ws_size,
                   hipStream_t stream)
{
    const void* X    = d_in[0];
    const void* W    = d_in[1];
    const void* bias = d_in[2];
    const void* ew   = d_in[3];
    const void* esrc = d_in[4];
    const void* edst = d_in[5];
    float* out = (float*)d_out;

    char* ws = (char*)d_ws;
    size_t off = 0;
    unsigned short* h  = (unsigned short*)(ws + off); off += (size_t)N_NODES * UNITS * 2;  // 51.2 MB
    unsigned short* Xb = (unsigned short*)(ws + off); off += (size_t)N_NODES * D_FEAT * 2; // 51.2 MB
    unsigned short* Wt = (unsigned short*)(ws + off); off += (size_t)D_FEAT * UNITS * 2;   // 0.5 MB
    int*   csr_src = (int*)(ws + off);   off += (size_t)N_EDGES * 4;                        // 6.4 MB
    float* csr_w   = (float*)(ws + off); off += (size_t)N_EDGES * 4;                        // 6.4 MB
    int*   counts  = (int*)(ws + off);   off += (size_t)N_NODES * 4;
    int*   row_ptr = (int*)(ws + off);   off += (size_t)(N_NODES + 1) * 4 + 12;
    int*   row_fill= (int*)(ws + off);   off += (size_t)N_NODES * 4;
    int*   flags   = (int*)(ws + off);

    // 0) detect dtypes
    GCN_detect<<<1, 64, 0, stream>>>(X, W, bias, ew, esrc, edst, flags);

    // 1) zero counts
    GCN_zero<<<(N_NODES + 255) / 256, 256, 0, stream>>>(counts);

    // 2) X -> bf16 (no-op if already bf16); W -> Wt[n][k] bf16
    GCN_xconv<<<4096, 256, 0, stream>>>(X, Xb, flags);
    {
        dim3 grid(D_FEAT / 64, UNITS / 64);
        GCN_wt<<<grid, 256, 0, stream>>>(W, Wt, flags);
    }

    // 3) h = X @ W via MFMA (col tiles fastest for A-tile L2 sharing)
    {
        dim3 grid(UNITS / 128, (N_NODES + 127) / 128);
        GCN_gemm_mfma<<<grid, 256, 0, stream>>>(X, Xb, Wt, h, flags);
    }

    // 4) histogram of dst
    GCN_hist<<<(N_EDGES + 255) / 256, 256, 0, stream>>>(edst, counts, flags);

    // 5) prefix sum -> row_ptr, row_fill
    GCN_scan<<<1, 256, 0, stream>>>(counts, row_ptr, row_fill);

    // 6) build CSR
    GCN_build<<<(N_EDGES + 255) / 256, 256, 0, stream>>>(esrc, edst, ew, row_fill,
                                                         csr_src, csr_w, flags);

    // 7) aggregate + bias + relu -> out
    GCNConv_86311662780630_kernel<<<(N_NODES + 3) / 4, 256, 0, stream>>>(
        h, row_ptr, csr_src, csr_w, bias, out, flags);
}